// Round 2
// baseline (1886.993 us; speedup 1.0000x reference)
//
#include <hip/hip_runtime.h>
#include <math.h>

#define B_ROWS 16384
#define H_DIM 7168
#define N_EXP 256
#define KT 32
#define MT 64
#define ET 128

// GEMM with f64 accumulation: logits[b][e] = sum_k hs[b][k]*w[e][k] (f32 inputs,
// products exact in f64, f64 adds) -> sigmoid in f64 -> round to f32 scores.
// This reproduces the reference's f64-compute-then-cast-to-f32 scores bit-exactly,
// so all downstream top-k comparisons (done in f32) match the reference exactly.
//
// 256 threads: tx in [0,16) -> 8 experts (2 per quarter), ty in [0,16) -> 4 rows.
// Tiles: M=64 rows, E=128 experts, K=32. Grid (16384/64, 256/128) = (256,2).
__global__ __launch_bounds__(256, 2)
void router_gemm_f64(const float* __restrict__ hs, const float* __restrict__ w,
                     float* __restrict__ scores) {
    // f64 LDS tiles, transposed. A stride 66 (even -> 16B-aligned double2 reads;
    // read banks 4k+8ty, 4 addrs x16-lane broadcast = conflict-free).
    // B in 4 quarter-arrays of 32 experts, stride 34: read lane-stride 16B ->
    // banks 4k+4tx -> 2 addrs/bank = 2-way = free (m136).
    __shared__ double As[KT][MT + 2];
    __shared__ double Ws[4][KT][34];
    const int t = threadIdx.x;
    const int tx = t & 15;
    const int ty = t >> 4;
    const int mBase = blockIdx.x * MT;
    const int eBase = blockIdx.y * ET;
    const float* hsp = hs + (size_t)mBase * H_DIM;
    const float* wp  = w  + (size_t)eBase * H_DIM;

    double acc[4][8];
#pragma unroll
    for (int r = 0; r < 4; ++r)
#pragma unroll
        for (int c = 0; c < 8; ++c) acc[r][c] = 0.0;

    // global prefetch of chunk 0 (A: 64x32 floats, B: 128x32 floats)
    float4 ha[2], wa[4];
#pragma unroll
    for (int i = 0; i < 2; ++i) {
        int flat = i * 1024 + t * 4;
        ha[i] = *(const float4*)(hsp + (size_t)(flat >> 5) * H_DIM + (flat & 31));
    }
#pragma unroll
    for (int i = 0; i < 4; ++i) {
        int flat = i * 1024 + t * 4;
        wa[i] = *(const float4*)(wp + (size_t)(flat >> 5) * H_DIM + (flat & 31));
    }

    const int NCHUNK = H_DIM / KT;  // 224
    for (int ch = 0; ch < NCHUNK; ++ch) {
        // registers -> LDS (convert f32->f64, transposed)
        {
            const int row = (t >> 3);       // 0..31
            const int kk  = 4 * (t & 7);    // 0,4,...,28
#pragma unroll
            for (int i = 0; i < 2; ++i) {
                const int rr = i * 32 + row;  // 0..63
                As[kk + 0][rr] = (double)ha[i].x;
                As[kk + 1][rr] = (double)ha[i].y;
                As[kk + 2][rr] = (double)ha[i].z;
                As[kk + 3][rr] = (double)ha[i].w;
            }
#pragma unroll
            for (int i = 0; i < 4; ++i) {
                // expert e = i*32 + row -> quarter q=i, column=row
                Ws[i][kk + 0][row] = (double)wa[i].x;
                Ws[i][kk + 1][row] = (double)wa[i].y;
                Ws[i][kk + 2][row] = (double)wa[i].z;
                Ws[i][kk + 3][row] = (double)wa[i].w;
            }
        }
        __syncthreads();
        // prefetch next chunk (overlaps with compute below)
        if (ch + 1 < NCHUNK) {
            const float* hp2 = hsp + (size_t)(ch + 1) * KT;
            const float* wp2 = wp  + (size_t)(ch + 1) * KT;
#pragma unroll
            for (int i = 0; i < 2; ++i) {
                int flat = i * 1024 + t * 4;
                ha[i] = *(const float4*)(hp2 + (size_t)(flat >> 5) * H_DIM + (flat & 31));
            }
#pragma unroll
            for (int i = 0; i < 4; ++i) {
                int flat = i * 1024 + t * 4;
                wa[i] = *(const float4*)(wp2 + (size_t)(flat >> 5) * H_DIM + (flat & 31));
            }
        }
        // compute: per k, 6x ds_read_b128 + 32 f64 FMA
#pragma unroll
        for (int k = 0; k < KT; ++k) {
            double2 a0 = *(const double2*)&As[k][ty * 4];
            double2 a1 = *(const double2*)&As[k][ty * 4 + 2];
            double2 b0 = *(const double2*)&Ws[0][k][tx * 2];
            double2 b1 = *(const double2*)&Ws[1][k][tx * 2];
            double2 b2 = *(const double2*)&Ws[2][k][tx * 2];
            double2 b3 = *(const double2*)&Ws[3][k][tx * 2];
            double a_[4] = {a0.x, a0.y, a1.x, a1.y};
            double b_[8] = {b0.x, b0.y, b1.x, b1.y, b2.x, b2.y, b3.x, b3.y};
#pragma unroll
            for (int r = 0; r < 4; ++r)
#pragma unroll
                for (int c = 0; c < 8; ++c)
                    acc[r][c] = fma(a_[r], b_[c], acc[r][c]);
        }
        __syncthreads();
    }
    // epilogue: f64 sigmoid, round to f32, store
#pragma unroll
    for (int r = 0; r < 4; ++r) {
        const int row = mBase + ty * 4 + r;
        float* dst = scores + (size_t)row * N_EXP + eBase;
#pragma unroll
        for (int q = 0; q < 4; ++q) {
            double s0 = 1.0 / (1.0 + exp(-acc[r][2 * q + 0]));
            double s1 = 1.0 / (1.0 + exp(-acc[r][2 * q + 1]));
            // expert column = q*32 + tx*2 + s
            *(float2*)(dst + q * 32 + tx * 2) = make_float2((float)s0, (float)s1);
        }
    }
}

// One wave (64 lanes) per row; 4 experts per lane (experts lane*4 .. lane*4+3).
// Group g = lane>>3 (8 lanes x 4 experts = 32 experts/group, 8 groups).
// All comparisons in f32, matching the reference's post-sigmoid f32 math exactly.
__global__ __launch_bounds__(256)
void router_topk_kernel(const float* __restrict__ scores, const float* __restrict__ bias,
                        float* __restrict__ out) {
    const int lane = threadIdx.x & 63;
    const int row = (blockIdx.x * blockDim.x + threadIdx.x) >> 6;

    float4 s4 = *(const float4*)(scores + (size_t)row * N_EXP + lane * 4);
    float4 b4 = *(const float4*)(bias + lane * 4);
    float sc[4]  = {s4.x, s4.y, s4.z, s4.w};
    float sfc[4] = {sc[0] + b4.x, sc[1] + b4.y, sc[2] + b4.z, sc[3] + b4.w};

    // per-group top-2 of scores_for_choice
    float m1 = -1e30f, m2 = -1e30f;
#pragma unroll
    for (int i = 0; i < 4; ++i) {
        float v = sfc[i];
        if (v > m1) { m2 = m1; m1 = v; }
        else if (v > m2) m2 = v;
    }
#pragma unroll
    for (int off = 1; off <= 4; off <<= 1) {  // butterfly within 8-lane group
        float o1 = __shfl_xor(m1, off);
        float o2 = __shfl_xor(m2, off);
        float n1 = fmaxf(m1, o1);
        float n2 = fmaxf(fminf(m1, o1), fmaxf(m2, o2));
        m1 = n1; m2 = n2;
    }
    float gs = m1 + m2;         // group score (all 8 lanes of the group agree)
    int g = lane >> 3;
    // rank of my group among the 8 (ties -> lower group index, like jax top_k)
    int rank = 0;
#pragma unroll
    for (int j = 0; j < 8; ++j) {
        float gj = __shfl(gs, j * 8);
        rank += (gj > gs || (gj == gs && j < g)) ? 1 : 0;
    }
    bool sel = rank < 4;
    float mv[4];
#pragma unroll
    for (int i = 0; i < 4; ++i) mv[i] = sel ? sfc[i] : 0.0f;

    // 8 rounds of wave-wide argmax (stable: ties -> lowest expert index)
    float wsum = 0.f;
    float myIdxF = 0.f, myW = 0.f;
    for (int it = 0; it < 8; ++it) {
        float bv = mv[0]; int bi = 0;
#pragma unroll
        for (int i = 1; i < 4; ++i)
            if (mv[i] > bv) { bv = mv[i]; bi = i; }
        int bidx = lane * 4 + bi;
        float bsc = sc[bi];   // un-biased sigmoid score rides along
#pragma unroll
        for (int off = 1; off <= 32; off <<= 1) {
            float ov = __shfl_xor(bv, off);
            int   oi = __shfl_xor(bidx, off);
            float os = __shfl_xor(bsc, off);
            if (ov > bv || (ov == bv && oi < bidx)) { bv = ov; bidx = oi; bsc = os; }
        }
        wsum += bsc;
        if (lane == it) { myIdxF = (float)bidx; myW = bsc; }
        if ((bidx >> 2) == lane) mv[bidx & 3] = -1e30f;  // owner clears winner
    }
    if (lane < 8) {
        out[(size_t)row * 8 + lane] = myIdxF;                                    // indices (as f32)
        out[(size_t)B_ROWS * 8 + (size_t)row * 8 + lane] = myW * (2.5f / wsum);  // weights
    }
}

extern "C" void kernel_launch(void* const* d_in, const int* in_sizes, int n_in,
                              void* d_out, int out_size, void* d_ws, size_t ws_size,
                              hipStream_t stream) {
    const float* hs   = (const float*)d_in[0];
    const float* w    = (const float*)d_in[1];
    const float* bias = (const float*)d_in[2];
    float* out = (float*)d_out;
    float* scores = (float*)d_ws;  // 16384*256*4 = 16 MB scratch

    dim3 g1(B_ROWS / MT, N_EXP / ET);  // (256, 2)
    router_gemm_f64<<<g1, 256, 0, stream>>>(hs, w, scores);
    router_topk_kernel<<<B_ROWS / 4, 256, 0, stream>>>(scores, bias, out);
}